// Round 1
// baseline (1879.639 us; speedup 1.0000x reference)
//
#include <hip/hip_runtime.h>
#include <cmath>

typedef __bf16 bf16x8 __attribute__((ext_vector_type(8)));
typedef float  f32x4  __attribute__((ext_vector_type(4)));
typedef float  f32x16 __attribute__((ext_vector_type(16)));

#define EPSF 1e-5f
// B=32, total in-ch=65, H=32, W=16 -> 512 pixels. cpt: (32,64,32,16) fp32.
// GEMM: z2[32,4096] = a[32,32768] @ plus_w[4096,32768]^T, 4 iterations.
// plus_w fp32 = 512 MiB. Iter0 converts it to a 256 MiB bf16 workspace copy
// (fused into the GEMM: the grid tiles W exactly once); iters 1-3 stream bf16.

// ---------------- head: convc/convp/convt + time MLP + poi + bn1(relu) + conv1 ----------------
__global__ __launch_bounds__(64) void head_kernel(
    const float* __restrict__ x,
    const float* __restrict__ cw, const float* __restrict__ cb,
    const float* __restrict__ pw, const float* __restrict__ pb,
    const float* __restrict__ tw, const float* __restrict__ tb,
    const float* __restrict__ tmw, const float* __restrict__ tmb,
    const float* __restrict__ tfw, const float* __restrict__ tfb,
    const float* __restrict__ poiw, const float* __restrict__ poib,
    const float* __restrict__ g1, const float* __restrict__ bb1,
    const float* __restrict__ m1, const float* __restrict__ v1,
    const float* __restrict__ w1, const float* __restrict__ b1c,
    float* __restrict__ cpt)
{
    int pix = blockIdx.x;            // 0..16383
    int b = pix >> 9, p = pix & 511;
    int t = threadIdx.x;             // 0..63

    __shared__ float xs[65];
    __shared__ float tx1[28];
    __shared__ float y[201];
    __shared__ float tx2s;

    for (int c = t; c < 65; c += 64)
        xs[c] = x[(b * 65 + c) * 512 + p];
    __syncthreads();

    if (t < 28) {
        float acc = tmb[t];
        for (int j = 0; j < 31; ++j) acc += tmw[t * 31 + j] * xs[34 + j];
        tx1[t] = fmaxf(acc, 0.f);
    }
    __syncthreads();
    if (t == 0) {
        float acc = tfb[0];
        for (int j = 0; j < 28; ++j) acc += tfw[j] * tx1[j];
        tx2s = fmaxf(acc, 0.f);
    }
    __syncthreads();
    float tx2 = tx2s;

    { // closeness: out ch 0..63, K=6 (x ch 0..5)
        float acc = cb[t];
        for (int j = 0; j < 6; ++j) acc += cw[t * 6 + j] * xs[j];
        y[t] = acc;
    }
    { // period: out ch 64..127, K=8 (x ch 6..13)
        float acc = pb[t];
        for (int j = 0; j < 8; ++j) acc += pw[t * 8 + j] * xs[6 + j];
        y[64 + t] = acc;
    }
    { // trend: out ch 128..191, K=8 (x ch 14..21)
        float acc = tb[t];
        for (int j = 0; j < 8; ++j) acc += tw[t * 8 + j] * xs[14 + j];
        y[128 + t] = acc;
    }
    if (t < 9) { // poi_time: out ch 192..200 (poi = x ch 22..33)
        float acc = poib[t];
        for (int j = 0; j < 12; ++j) acc += poiw[t * 12 + j] * (tx2 * xs[22 + j]);
        y[192 + t] = acc;
    }
    // bn1(relu(.)) applied by the same thread that wrote each channel
    for (int c = t; c < 201; c += 64) {
        float s  = g1[c] * rsqrtf(v1[c] + EPSF);
        float tt = bb1[c] - m1[c] * s;
        y[c] = fmaxf(y[c], 0.f) * s + tt;
    }
    __syncthreads();

    float acc = b1c[t];
    const float* wrow = w1 + t * 201;
    for (int c = 0; c < 201; ++c) acc += wrow[c] * y[c];
    cpt[(b * 64 + t) * 512 + p] = acc;
}

// ---------------- prep: a_bf = bn1(relu(cpt)) as bf16 (GEMM A); z2 = plus_b broadcast ----------------
__global__ void prep_kernel(const float* __restrict__ cpt,
                            const float* __restrict__ g, const float* __restrict__ bb,
                            const float* __restrict__ m, const float* __restrict__ v,
                            const float* __restrict__ plus_b,
                            __bf16* __restrict__ a_bf, float* __restrict__ z2)
{
    int i = blockIdx.x * blockDim.x + threadIdx.x;
    if (i < 32 * 64 * 512) {
        int c = (i >> 9) & 63;
        float s  = g[c] * rsqrtf(v[c] + EPSF);
        float tt = bb[c] - m[c] * s;
        a_bf[i] = (__bf16)(fmaxf(cpt[i], 0.f) * s + tt);   // bn(relu(x))
    }
    if (i < 32 * 4096) {
        z2[i] = plus_b[i & 4095];
    }
}

// ---------------- GEMM (fallback, fp32 W stream): z2[b,n] += sum_k a[b,k]*W[n,k] ----------------
// MFMA 32x32x16 bf16, split-K=16, atomics. Used only when ws_size can't hold the bf16 W cache.
__global__ __launch_bounds__(256) void gemm_kernel(const __bf16* __restrict__ a_bf,
                                                   const float* __restrict__ plus_w,
                                                   float* __restrict__ z2)
{
    int wave = threadIdx.x >> 6;
    int lane = threadIdx.x & 63;
    int gw = blockIdx.x * 4 + wave;   // 0..2047
    int nt = gw & 127;                // 128 n-tiles of 32
    int ks = gw >> 7;                 // 16 K-splits of 2048
    int r32 = lane & 31;
    int hi  = lane >> 5;
    int n = nt * 32 + r32;
    long k0 = (long)ks * 2048 + hi * 8;

    const float*  wp = plus_w + (long)n * 32768 + k0;
    const bf16x8* ap = (const bf16x8*)(a_bf + (long)r32 * 32768 + k0);

    f32x16 acc = {};
#pragma unroll 4
    for (int it = 0; it < 128; ++it) {          // 128 * K16 = 2048
        f32x4 w0 = *(const f32x4*)(wp + it * 16);
        f32x4 w1 = *(const f32x4*)(wp + it * 16 + 4);
        bf16x8 bfr;
#pragma unroll
        for (int j = 0; j < 4; ++j) { bfr[j] = (__bf16)w0[j]; bfr[j + 4] = (__bf16)w1[j]; }
        bf16x8 afr = ap[it * 2];
        acc = __builtin_amdgcn_mfma_f32_32x32x16_bf16(afr, bfr, acc, 0, 0, 0);
    }
    // C/D layout (m74/m101): col(n)=lane&31, row(b)=(reg&3)+8*(reg>>2)+4*(lane>>5)
#pragma unroll
    for (int r = 0; r < 16; ++r) {
        int brow = (r & 3) + 8 * (r >> 2) + 4 * hi;
        atomicAdd(&z2[brow * 4096 + n], acc[r]);
    }
}

// ---------------- GEMM iter 0 (cached path): fp32 W stream + convert + STORE bf16 copy + MFMA ----
// The grid tiles W exactly once (every (n,k) loaded by exactly one lane), so the
// bf16 store produces a complete, bit-identical-to-register copy of W for iters 1-3.
__global__ __launch_bounds__(256) void gemm_convstore_kernel(const __bf16* __restrict__ a_bf,
                                                             const float* __restrict__ plus_w,
                                                             __bf16* __restrict__ w_bf,
                                                             float* __restrict__ z2)
{
    int wave = threadIdx.x >> 6;
    int lane = threadIdx.x & 63;
    int gw = blockIdx.x * 4 + wave;
    int nt = gw & 127;
    int ks = gw >> 7;
    int r32 = lane & 31;
    int hi  = lane >> 5;
    int n = nt * 32 + r32;
    long k0 = (long)ks * 2048 + hi * 8;

    const float*  wp  = plus_w + (long)n * 32768 + k0;
    __bf16*       wbp = w_bf   + (long)n * 32768 + k0;
    const bf16x8* ap  = (const bf16x8*)(a_bf + (long)r32 * 32768 + k0);

    f32x16 acc = {};
#pragma unroll 4
    for (int it = 0; it < 128; ++it) {
        f32x4 w0 = *(const f32x4*)(wp + it * 16);
        f32x4 w1 = *(const f32x4*)(wp + it * 16 + 4);
        bf16x8 bfr;
#pragma unroll
        for (int j = 0; j < 4; ++j) { bfr[j] = (__bf16)w0[j]; bfr[j + 4] = (__bf16)w1[j]; }
        *(bf16x8*)(wbp + it * 16) = bfr;        // 16B store, same tiling as the loads
        bf16x8 afr = ap[it * 2];
        acc = __builtin_amdgcn_mfma_f32_32x32x16_bf16(afr, bfr, acc, 0, 0, 0);
    }
#pragma unroll
    for (int r = 0; r < 16; ++r) {
        int brow = (r & 3) + 8 * (r >> 2) + 4 * hi;
        atomicAdd(&z2[brow * 4096 + n], acc[r]);
    }
}

// ---------------- GEMM iters 1-3 (cached path): bf16 W stream — half the HBM bytes -------------
__global__ __launch_bounds__(256) void gemm_bf_kernel(const __bf16* __restrict__ a_bf,
                                                      const __bf16* __restrict__ w_bf,
                                                      float* __restrict__ z2)
{
    int wave = threadIdx.x >> 6;
    int lane = threadIdx.x & 63;
    int gw = blockIdx.x * 4 + wave;
    int nt = gw & 127;
    int ks = gw >> 7;
    int r32 = lane & 31;
    int hi  = lane >> 5;
    int n = nt * 32 + r32;
    long k0 = (long)ks * 2048 + hi * 8;

    const bf16x8* wpb = (const bf16x8*)(w_bf + (long)n * 32768 + k0);
    const bf16x8* ap  = (const bf16x8*)(a_bf + (long)r32 * 32768 + k0);

    f32x16 acc = {};
#pragma unroll 8
    for (int it = 0; it < 128; ++it) {          // 1 W load + 1 A load + 1 MFMA per K16
        acc = __builtin_amdgcn_mfma_f32_32x32x16_bf16(ap[it * 2], wpb[it * 2], acc, 0, 0, 0);
    }
#pragma unroll
    for (int r = 0; r < 16; ++r) {
        int brow = (r & 3) + 8 * (r >> 2) + 4 * hi;
        atomicAdd(&z2[brow * 4096 + n], acc[r]);
    }
}

// ---------------- conv3x3 #1: z1 = conv(relu(bn1(cpt)), rp_conv1_w) + b, 56 out ch ----------------
__global__ __launch_bounds__(512) void conv1_kernel(const float* __restrict__ cpt,
                                                    const float* __restrict__ g, const float* __restrict__ bb,
                                                    const float* __restrict__ m, const float* __restrict__ v,
                                                    const float* __restrict__ w,
                                                    const float* __restrict__ bias,
                                                    float* __restrict__ z1)
{
    int b  = blockIdx.x;        // 0..31
    int og = blockIdx.y;        // 0..13 (4 out-ch each)
    int p  = threadIdx.x;       // 0..511
    int h = p >> 4, wc = p & 15;
    int o0 = og * 4;

    __shared__ float ss[64], ts[64];
    if (p < 64) {
        float s = g[p] * rsqrtf(v[p] + EPSF);
        ss[p] = s;
        ts[p] = bb[p] - m[p] * s;
    }
    __syncthreads();

    float a0 = bias[o0], a1 = bias[o0 + 1], a2 = bias[o0 + 2], a3 = bias[o0 + 3];
    const float* rb = cpt + b * 64 * 512;
    for (int c = 0; c < 64; ++c) {
        const float* rc = rb + c * 512;
        float s = ss[c], tt = ts[c];
        float rv[9];
#pragma unroll
        for (int dh = -1; dh <= 1; ++dh)
#pragma unroll
            for (int dw = -1; dw <= 1; ++dw) {
                int hh = h + dh, ww = wc + dw;
                bool ok = (hh >= 0) & (hh < 32) & (ww >= 0) & (ww < 16);
                rv[(dh + 1) * 3 + (dw + 1)] = ok ? fmaxf(rc[hh * 16 + ww] * s + tt, 0.f) : 0.f;
            }
#pragma unroll
        for (int tp = 0; tp < 9; ++tp) {
            a0 += rv[tp] * w[((o0    ) * 64 + c) * 9 + tp];
            a1 += rv[tp] * w[((o0 + 1) * 64 + c) * 9 + tp];
            a2 += rv[tp] * w[((o0 + 2) * 64 + c) * 9 + tp];
            a3 += rv[tp] * w[((o0 + 3) * 64 + c) * 9 + tp];
        }
    }
    float* zb = z1 + ((b * 56 + o0) * 512) + p;
    zb[0] = a0; zb[512] = a1; zb[1024] = a2; zb[1536] = a3;
}

// ---------------- prep2: z3 = relu(bn2(concat(z1, z2))) -> bf16 ----------------
__global__ void prep2_kernel(const float* __restrict__ z1, const float* __restrict__ z2,
                             const float* __restrict__ g, const float* __restrict__ bb,
                             const float* __restrict__ m, const float* __restrict__ v,
                             __bf16* __restrict__ z3)
{
    int i = blockIdx.x * blockDim.x + threadIdx.x;
    if (i >= 32 * 64 * 512) return;
    int b = i >> 15, c = (i >> 9) & 63, p = i & 511;
    float val = (c < 56) ? z1[(b * 56 + c) * 512 + p]
                         : z2[b * 4096 + (c - 56) * 512 + p];
    float s  = g[c] * rsqrtf(v[c] + EPSF);
    float tt = bb[c] - m[c] * s;
    z3[i] = (__bf16)fmaxf(val * s + tt, 0.f);
}

// ---------------- conv3x3 #2: cpt += conv(z3, rp_conv2_w) + b (in-place residual) -----------
__global__ __launch_bounds__(512) void conv2_kernel(const __bf16* __restrict__ z3,
                                                    const float* __restrict__ w,
                                                    const float* __restrict__ bias,
                                                    float* __restrict__ cpt)
{
    int b  = blockIdx.x;        // 0..31
    int og = blockIdx.y;        // 0..15
    int p  = threadIdx.x;       // 0..511
    int h = p >> 4, wc = p & 15;
    int o0 = og * 4;
    float a0 = bias[o0], a1 = bias[o0 + 1], a2 = bias[o0 + 2], a3 = bias[o0 + 3];
    const __bf16* rb = z3 + b * 64 * 512;
    for (int c = 0; c < 64; ++c) {
        const __bf16* rc = rb + c * 512;
        float rv[9];
#pragma unroll
        for (int dh = -1; dh <= 1; ++dh)
#pragma unroll
            for (int dw = -1; dw <= 1; ++dw) {
                int hh = h + dh, ww = wc + dw;
                bool ok = (hh >= 0) & (hh < 32) & (ww >= 0) & (ww < 16);
                rv[(dh + 1) * 3 + (dw + 1)] = ok ? (float)rc[hh * 16 + ww] : 0.f;
            }
#pragma unroll
        for (int tp = 0; tp < 9; ++tp) {
            a0 += rv[tp] * w[((o0    ) * 64 + c) * 9 + tp];
            a1 += rv[tp] * w[((o0 + 1) * 64 + c) * 9 + tp];
            a2 += rv[tp] * w[((o0 + 2) * 64 + c) * 9 + tp];
            a3 += rv[tp] * w[((o0 + 3) * 64 + c) * 9 + tp];
        }
    }
    float* cb_ = cpt + ((b * 64 + o0) * 512) + p;
    cb_[0]    += a0;
    cb_[512]  += a1;
    cb_[1024] += a2;
    cb_[1536] += a3;
}

// ---------------- tail: out = tanh(conv2(bn2(relu(cpt)))) -> fp32 ----------------
__global__ void tail_kernel(const float* __restrict__ cpt,
                            const float* __restrict__ g, const float* __restrict__ bb,
                            const float* __restrict__ m, const float* __restrict__ v,
                            const float* __restrict__ w2, const float* __restrict__ b2,
                            float* __restrict__ out)
{
    int i = blockIdx.x * blockDim.x + threadIdx.x;
    if (i >= 32 * 512) return;
    int b = i >> 9, p = i & 511;
    float a0 = b2[0], a1 = b2[1];
    for (int c = 0; c < 64; ++c) {
        float s  = g[c] * rsqrtf(v[c] + EPSF);
        float tt = bb[c] - m[c] * s;
        float y = fmaxf(cpt[(b * 64 + c) * 512 + p], 0.f) * s + tt;
        a0 += w2[c] * y;
        a1 += w2[64 + c] * y;
    }
    out[(b * 2 + 0) * 512 + p] = tanhf(a0);
    out[(b * 2 + 1) * 512 + p] = tanhf(a1);
}

extern "C" void kernel_launch(void* const* d_in, const int* in_sizes, int n_in,
                              void* d_out, int out_size, void* d_ws, size_t ws_size,
                              hipStream_t stream)
{
#define IN(i) ((const float*)d_in[i])
    // workspace layout:
    //   [0,      4 MiB) cpt   : 32*64*512 fp32
    //   [4 MiB,  6 MiB) a_bf  : 32*64*512 bf16  (GEMM A) — ALIASED with z3 (safe: a_bf
    //                           consumed by gemm before prep2 writes z3; z3 consumed by
    //                           conv2 before next iteration's prep rewrites a_bf)
    //   [6 MiB,  9.5MiB) z1   : 32*56*512 fp32
    //   [9.5MiB, 10 MiB) z2   : 32*4096  fp32
    //   [10 MiB, 266 MiB) w_bf: 4096*32768 bf16 — cached bf16 copy of plus_w,
    //                           rebuilt every call by iter-0's gemm_convstore (so
    //                           workspace re-poisoning between calls is harmless).
    float*  cpt  = (float*)d_ws;
    __bf16* a_bf = (__bf16*)((char*)d_ws + (size_t)4 * 1024 * 1024);
    __bf16* z3   = a_bf;
    float*  z1   = (float*)((char*)d_ws + (size_t)6 * 1024 * 1024);
    float*  z2   = z1 + 32 * 56 * 512;
    __bf16* w_bf = (__bf16*)((char*)d_ws + (size_t)10 * 1024 * 1024);

    const bool cacheW = ws_size >= (size_t)266 * 1024 * 1024;

    head_kernel<<<16384, 64, 0, stream>>>(
        IN(0), IN(1), IN(2), IN(3), IN(4), IN(5), IN(6), IN(7), IN(8), IN(9), IN(10),
        IN(11), IN(12), IN(13), IN(14), IN(15), IN(16), IN(17), IN(18), cpt);

    for (int it = 0; it < 4; ++it) {
        prep_kernel<<<4096, 256, 0, stream>>>(cpt, IN(19), IN(20), IN(21), IN(22),
                                              IN(32), a_bf, z2);
        if (cacheW) {
            if (it == 0)
                gemm_convstore_kernel<<<512, 256, 0, stream>>>(a_bf, IN(31), w_bf, z2);
            else
                gemm_bf_kernel<<<512, 256, 0, stream>>>(a_bf, w_bf, z2);
        } else {
            gemm_kernel<<<512, 256, 0, stream>>>(a_bf, IN(31), z2);
        }
        conv1_kernel<<<dim3(32, 14), 512, 0, stream>>>(cpt, IN(19), IN(20), IN(21), IN(22),
                                                       IN(23), IN(24), z1);
        prep2_kernel<<<4096, 256, 0, stream>>>(z1, z2, IN(25), IN(26), IN(27), IN(28), z3);
        conv2_kernel<<<dim3(32, 16), 512, 0, stream>>>(z3, IN(29), IN(30), cpt);
    }

    tail_kernel<<<64, 256, 0, stream>>>(cpt, IN(33), IN(34), IN(35), IN(36),
                                        IN(37), IN(38), (float*)d_out);
#undef IN
}

// Round 2
// 1832.496 us; speedup vs baseline: 1.0257x; 1.0257x over previous
//
#include <hip/hip_runtime.h>
#include <cmath>
#include <cstdint>

typedef __bf16 bf16x8 __attribute__((ext_vector_type(8)));
typedef float  f32x4  __attribute__((ext_vector_type(4)));
typedef float  f32x16 __attribute__((ext_vector_type(16)));

#define EPSF 1e-5f
// B=32, total in-ch=65, H=32, W=16 -> 512 pixels. cpt: (32,64,32,16) fp32.
// GEMM: z2[32,4096] = a[32,32768] @ plus_w[4096,32768]^T, 4 iterations.
// plus_w fp32 (512 MiB) is converted ONCE per call to bf16 (256 MiB workspace);
// all 4 GEMMs stream the bf16 copy through per-wave global_load_lds rings
// (16 outstanding 1-KiB DMAs per wave) so the stream is BW-bound, not latency-bound.

// async 16B global->LDS (CK-style addrspace casts; LDS dest = wave-uniform base + lane*16)
__device__ __forceinline__ void gll16(const void* g, void* l)
{
    __builtin_amdgcn_global_load_lds(
        reinterpret_cast<const __attribute__((address_space(1))) void*>(
            reinterpret_cast<uintptr_t>(g)),
        reinterpret_cast<__attribute__((address_space(3))) void*>(
            reinterpret_cast<uintptr_t>(l)),
        16, 0, 0);
}

// ---------------- head: convc/convp/convt + time MLP + poi + bn1(relu) + conv1 ----------------
__global__ __launch_bounds__(64) void head_kernel(
    const float* __restrict__ x,
    const float* __restrict__ cw, const float* __restrict__ cb,
    const float* __restrict__ pw, const float* __restrict__ pb,
    const float* __restrict__ tw, const float* __restrict__ tb,
    const float* __restrict__ tmw, const float* __restrict__ tmb,
    const float* __restrict__ tfw, const float* __restrict__ tfb,
    const float* __restrict__ poiw, const float* __restrict__ poib,
    const float* __restrict__ g1, const float* __restrict__ bb1,
    const float* __restrict__ m1, const float* __restrict__ v1,
    const float* __restrict__ w1, const float* __restrict__ b1c,
    float* __restrict__ cpt)
{
    int pix = blockIdx.x;            // 0..16383
    int b = pix >> 9, p = pix & 511;
    int t = threadIdx.x;             // 0..63

    __shared__ float xs[65];
    __shared__ float tx1[28];
    __shared__ float y[201];
    __shared__ float tx2s;

    for (int c = t; c < 65; c += 64)
        xs[c] = x[(b * 65 + c) * 512 + p];
    __syncthreads();

    if (t < 28) {
        float acc = tmb[t];
        for (int j = 0; j < 31; ++j) acc += tmw[t * 31 + j] * xs[34 + j];
        tx1[t] = fmaxf(acc, 0.f);
    }
    __syncthreads();
    if (t == 0) {
        float acc = tfb[0];
        for (int j = 0; j < 28; ++j) acc += tfw[j] * tx1[j];
        tx2s = fmaxf(acc, 0.f);
    }
    __syncthreads();
    float tx2 = tx2s;

    { // closeness: out ch 0..63, K=6 (x ch 0..5)
        float acc = cb[t];
        for (int j = 0; j < 6; ++j) acc += cw[t * 6 + j] * xs[j];
        y[t] = acc;
    }
    { // period: out ch 64..127, K=8 (x ch 6..13)
        float acc = pb[t];
        for (int j = 0; j < 8; ++j) acc += pw[t * 8 + j] * xs[6 + j];
        y[64 + t] = acc;
    }
    { // trend: out ch 128..191, K=8 (x ch 14..21)
        float acc = tb[t];
        for (int j = 0; j < 8; ++j) acc += tw[t * 8 + j] * xs[14 + j];
        y[128 + t] = acc;
    }
    if (t < 9) { // poi_time: out ch 192..200 (poi = x ch 22..33)
        float acc = poib[t];
        for (int j = 0; j < 12; ++j) acc += poiw[t * 12 + j] * (tx2 * xs[22 + j]);
        y[192 + t] = acc;
    }
    // bn1(relu(.)) applied by the same thread that wrote each channel
    for (int c = t; c < 201; c += 64) {
        float s  = g1[c] * rsqrtf(v1[c] + EPSF);
        float tt = bb1[c] - m1[c] * s;
        y[c] = fmaxf(y[c], 0.f) * s + tt;
    }
    __syncthreads();

    float acc = b1c[t];
    const float* wrow = w1 + t * 201;
    for (int c = 0; c < 201; ++c) acc += wrow[c] * y[c];
    cpt[(b * 64 + t) * 512 + p] = acc;
}

// ---------------- wconv: plus_w fp32 -> bf16 workspace copy (once per call) ----------------
__global__ __launch_bounds__(256) void wconv_kernel(const float* __restrict__ w,
                                                    __bf16* __restrict__ wb)
{
    long i = ((long)blockIdx.x * 256 + threadIdx.x) * 8;   // 2^27 elements total
    f32x4 a = *(const f32x4*)(w + i);
    f32x4 b = *(const f32x4*)(w + i + 4);
    bf16x8 o;
#pragma unroll
    for (int j = 0; j < 4; ++j) { o[j] = (__bf16)a[j]; o[j + 4] = (__bf16)b[j]; }
    *(bf16x8*)(wb + i) = o;
}

// ---------------- prep: a_bf = bn1(relu(cpt)) as bf16 (GEMM A); z2 = plus_b broadcast ----------------
__global__ void prep_kernel(const float* __restrict__ cpt,
                            const float* __restrict__ g, const float* __restrict__ bb,
                            const float* __restrict__ m, const float* __restrict__ v,
                            const float* __restrict__ plus_b,
                            __bf16* __restrict__ a_bf, float* __restrict__ z2)
{
    int i = blockIdx.x * blockDim.x + threadIdx.x;
    if (i < 32 * 64 * 512) {
        int c = (i >> 9) & 63;
        float s  = g[c] * rsqrtf(v[c] + EPSF);
        float tt = bb[c] - m[c] * s;
        a_bf[i] = (__bf16)(fmaxf(cpt[i], 0.f) * s + tt);   // bn(relu(x))
    }
    if (i < 32 * 4096) {
        z2[i] = plus_b[i & 4095];
    }
}

// ---------------- GEMM (fallback, fp32 W stream): used only if ws can't hold w_bf ----------------
__global__ __launch_bounds__(256) void gemm_kernel(const __bf16* __restrict__ a_bf,
                                                   const float* __restrict__ plus_w,
                                                   float* __restrict__ z2)
{
    int wave = threadIdx.x >> 6;
    int lane = threadIdx.x & 63;
    int gw = blockIdx.x * 4 + wave;   // 0..2047
    int nt = gw & 127;                // 128 n-tiles of 32
    int ks = gw >> 7;                 // 16 K-splits of 2048
    int r32 = lane & 31;
    int hi  = lane >> 5;
    int n = nt * 32 + r32;
    long k0 = (long)ks * 2048 + hi * 8;

    const float*  wp = plus_w + (long)n * 32768 + k0;
    const bf16x8* ap = (const bf16x8*)(a_bf + (long)r32 * 32768 + k0);

    f32x16 acc = {};
#pragma unroll 4
    for (int it = 0; it < 128; ++it) {          // 128 * K16 = 2048
        f32x4 w0 = *(const f32x4*)(wp + it * 16);
        f32x4 w1 = *(const f32x4*)(wp + it * 16 + 4);
        bf16x8 bfr;
#pragma unroll
        for (int j = 0; j < 4; ++j) { bfr[j] = (__bf16)w0[j]; bfr[j + 4] = (__bf16)w1[j]; }
        bf16x8 afr = ap[it * 2];
        acc = __builtin_amdgcn_mfma_f32_32x32x16_bf16(afr, bfr, acc, 0, 0, 0);
    }
#pragma unroll
    for (int r = 0; r < 16; ++r) {
        int brow = (r & 3) + 8 * (r >> 2) + 4 * hi;
        atomicAdd(&z2[brow * 4096 + n], acc[r]);
    }
}

// ---------------- GEMM (bf16 W, LDS-ring deep pipeline) ----------------
// 512 blocks x 4 waves; wave = one 32-col n-tile x one K-split of 2048.
// Per wave: 8-slot x 1 KiB ring each for W and A, filled by global_load_lds
// (lane l deposits its own 16 B MFMA fragment at base+l*16; identity readback).
// 16 outstanding DMAs/wave -> 128 KiB in flight per CU -> HBM BW-bound.
// No __syncthreads: each wave owns its LDS slice exclusively.
__global__ __launch_bounds__(256) void gemm_lds_kernel(const __bf16* __restrict__ a_bf,
                                                       const __bf16* __restrict__ w_bf,
                                                       float* __restrict__ z2)
{
    __shared__ __bf16 ring[4][2][8][512];   // [wave][W/A][slot][lane*8] = 64 KiB

    int wave = threadIdx.x >> 6;
    int lane = threadIdx.x & 63;
    int gw = blockIdx.x * 4 + wave;   // 0..2047
    int nt = gw & 127;                // n-tile of 32 cols
    int ks = gw >> 7;                 // K-split of 2048
    int r32 = lane & 31;
    int hi  = lane >> 5;
    int n = nt * 32 + r32;
    long k0 = (long)ks * 2048 + hi * 8;

    const __bf16* wsrc = w_bf + (long)n   * 32768 + k0;  // per-lane W fragment source
    const __bf16* asrc = a_bf + (long)r32 * 32768 + k0;  // per-lane A fragment source (L2-hot)
    __bf16* wr = &ring[wave][0][0][0];
    __bf16* ar = &ring[wave][1][0][0];

    // prologue: fill all 8 slots (16 outstanding glls, pair order W,A per slot)
#pragma unroll
    for (int s = 0; s < 8; ++s) {
        gll16(wsrc + s * 16, wr + s * 512);
        gll16(asrc + s * 16, ar + s * 512);
    }

    f32x16 acc = {};
    // steady state: wait oldest pair, consume, reissue slot for it+8
    for (int it = 0; it < 120; ++it) {
        int slot = it & 7;
        asm volatile("s_waitcnt vmcnt(14)" ::: "memory");
        __builtin_amdgcn_sched_barrier(0);
        bf16x8 bfr = *(const bf16x8*)(wr + slot * 512 + lane * 8);
        bf16x8 afr = *(const bf16x8*)(ar + slot * 512 + lane * 8);
        acc = __builtin_amdgcn_mfma_f32_32x32x16_bf16(afr, bfr, acc, 0, 0, 0);
        gll16(wsrc + (it + 8) * 16, wr + slot * 512);
        gll16(asrc + (it + 8) * 16, ar + slot * 512);
    }
    // tail: drain and consume last 8 slots
    asm volatile("s_waitcnt vmcnt(0)" ::: "memory");
    __builtin_amdgcn_sched_barrier(0);
#pragma unroll
    for (int it = 120; it < 128; ++it) {
        int slot = it & 7;
        bf16x8 bfr = *(const bf16x8*)(wr + slot * 512 + lane * 8);
        bf16x8 afr = *(const bf16x8*)(ar + slot * 512 + lane * 8);
        acc = __builtin_amdgcn_mfma_f32_32x32x16_bf16(afr, bfr, acc, 0, 0, 0);
    }

    // C/D layout (m74/m101): col(n)=lane&31, row(b)=(reg&3)+8*(reg>>2)+4*(lane>>5)
#pragma unroll
    for (int r = 0; r < 16; ++r) {
        int brow = (r & 3) + 8 * (r >> 2) + 4 * hi;
        atomicAdd(&z2[brow * 4096 + n], acc[r]);
    }
}

// ---------------- conv3x3 #1: z1 = conv(relu(bn1(cpt)), rp_conv1_w) + b, 56 out ch ----------------
__global__ __launch_bounds__(512) void conv1_kernel(const float* __restrict__ cpt,
                                                    const float* __restrict__ g, const float* __restrict__ bb,
                                                    const float* __restrict__ m, const float* __restrict__ v,
                                                    const float* __restrict__ w,
                                                    const float* __restrict__ bias,
                                                    float* __restrict__ z1)
{
    int b  = blockIdx.x;        // 0..31
    int og = blockIdx.y;        // 0..13 (4 out-ch each)
    int p  = threadIdx.x;       // 0..511
    int h = p >> 4, wc = p & 15;
    int o0 = og * 4;

    __shared__ float ss[64], ts[64];
    if (p < 64) {
        float s = g[p] * rsqrtf(v[p] + EPSF);
        ss[p] = s;
        ts[p] = bb[p] - m[p] * s;
    }
    __syncthreads();

    float a0 = bias[o0], a1 = bias[o0 + 1], a2 = bias[o0 + 2], a3 = bias[o0 + 3];
    const float* rb = cpt + b * 64 * 512;
    for (int c = 0; c < 64; ++c) {
        const float* rc = rb + c * 512;
        float s = ss[c], tt = ts[c];
        float rv[9];
#pragma unroll
        for (int dh = -1; dh <= 1; ++dh)
#pragma unroll
            for (int dw = -1; dw <= 1; ++dw) {
                int hh = h + dh, ww = wc + dw;
                bool ok = (hh >= 0) & (hh < 32) & (ww >= 0) & (ww < 16);
                rv[(dh + 1) * 3 + (dw + 1)] = ok ? fmaxf(rc[hh * 16 + ww] * s + tt, 0.f) : 0.f;
            }
#pragma unroll
        for (int tp = 0; tp < 9; ++tp) {
            a0 += rv[tp] * w[((o0    ) * 64 + c) * 9 + tp];
            a1 += rv[tp] * w[((o0 + 1) * 64 + c) * 9 + tp];
            a2 += rv[tp] * w[((o0 + 2) * 64 + c) * 9 + tp];
            a3 += rv[tp] * w[((o0 + 3) * 64 + c) * 9 + tp];
        }
    }
    float* zb = z1 + ((b * 56 + o0) * 512) + p;
    zb[0] = a0; zb[512] = a1; zb[1024] = a2; zb[1536] = a3;
}

// ---------------- prep2: z3 = relu(bn2(concat(z1, z2))) -> bf16 ----------------
__global__ void prep2_kernel(const float* __restrict__ z1, const float* __restrict__ z2,
                             const float* __restrict__ g, const float* __restrict__ bb,
                             const float* __restrict__ m, const float* __restrict__ v,
                             __bf16* __restrict__ z3)
{
    int i = blockIdx.x * blockDim.x + threadIdx.x;
    if (i >= 32 * 64 * 512) return;
    int b = i >> 15, c = (i >> 9) & 63, p = i & 511;
    float val = (c < 56) ? z1[(b * 56 + c) * 512 + p]
                         : z2[b * 4096 + (c - 56) * 512 + p];
    float s  = g[c] * rsqrtf(v[c] + EPSF);
    float tt = bb[c] - m[c] * s;
    z3[i] = (__bf16)fmaxf(val * s + tt, 0.f);
}

// ---------------- conv3x3 #2: cpt += conv(z3, rp_conv2_w) + b (in-place residual) -----------
__global__ __launch_bounds__(512) void conv2_kernel(const __bf16* __restrict__ z3,
                                                    const float* __restrict__ w,
                                                    const float* __restrict__ bias,
                                                    float* __restrict__ cpt)
{
    int b  = blockIdx.x;        // 0..31
    int og = blockIdx.y;        // 0..15
    int p  = threadIdx.x;       // 0..511
    int h = p >> 4, wc = p & 15;
    int o0 = og * 4;
    float a0 = bias[o0], a1 = bias[o0 + 1], a2 = bias[o0 + 2], a3 = bias[o0 + 3];
    const __bf16* rb = z3 + b * 64 * 512;
    for (int c = 0; c < 64; ++c) {
        const __bf16* rc = rb + c * 512;
        float rv[9];
#pragma unroll
        for (int dh = -1; dh <= 1; ++dh)
#pragma unroll
            for (int dw = -1; dw <= 1; ++dw) {
                int hh = h + dh, ww = wc + dw;
                bool ok = (hh >= 0) & (hh < 32) & (ww >= 0) & (ww < 16);
                rv[(dh + 1) * 3 + (dw + 1)] = ok ? (float)rc[hh * 16 + ww] : 0.f;
            }
#pragma unroll
        for (int tp = 0; tp < 9; ++tp) {
            a0 += rv[tp] * w[((o0    ) * 64 + c) * 9 + tp];
            a1 += rv[tp] * w[((o0 + 1) * 64 + c) * 9 + tp];
            a2 += rv[tp] * w[((o0 + 2) * 64 + c) * 9 + tp];
            a3 += rv[tp] * w[((o0 + 3) * 64 + c) * 9 + tp];
        }
    }
    float* cb_ = cpt + ((b * 64 + o0) * 512) + p;
    cb_[0]    += a0;
    cb_[512]  += a1;
    cb_[1024] += a2;
    cb_[1536] += a3;
}

// ---------------- tail: out = tanh(conv2(bn2(relu(cpt)))) -> fp32 ----------------
__global__ void tail_kernel(const float* __restrict__ cpt,
                            const float* __restrict__ g, const float* __restrict__ bb,
                            const float* __restrict__ m, const float* __restrict__ v,
                            const float* __restrict__ w2, const float* __restrict__ b2,
                            float* __restrict__ out)
{
    int i = blockIdx.x * blockDim.x + threadIdx.x;
    if (i >= 32 * 512) return;
    int b = i >> 9, p = i & 511;
    float a0 = b2[0], a1 = b2[1];
    for (int c = 0; c < 64; ++c) {
        float s  = g[c] * rsqrtf(v[c] + EPSF);
        float tt = bb[c] - m[c] * s;
        float y = fmaxf(cpt[(b * 64 + c) * 512 + p], 0.f) * s + tt;
        a0 += w2[c] * y;
        a1 += w2[64 + c] * y;
    }
    out[(b * 2 + 0) * 512 + p] = tanhf(a0);
    out[(b * 2 + 1) * 512 + p] = tanhf(a1);
}

extern "C" void kernel_launch(void* const* d_in, const int* in_sizes, int n_in,
                              void* d_out, int out_size, void* d_ws, size_t ws_size,
                              hipStream_t stream)
{
#define IN(i) ((const float*)d_in[i])
    // workspace layout:
    //   [0,      4 MiB) cpt   : 32*64*512 fp32
    //   [4 MiB,  6 MiB) a_bf  : 32*64*512 bf16  (GEMM A) — ALIASED with z3 (safe: a_bf
    //                           consumed by gemm before prep2 writes z3; z3 consumed by
    //                           conv2 before next iteration's prep rewrites a_bf)
    //   [6 MiB,  9.5MiB) z1   : 32*56*512 fp32
    //   [9.5MiB, 10 MiB) z2   : 32*4096  fp32
    //   [10 MiB, 266 MiB) w_bf: 4096*32768 bf16 — bf16 copy of plus_w, rebuilt every
    //                           call by wconv_kernel (so workspace re-poisoning
    //                           between calls is harmless).
    float*  cpt  = (float*)d_ws;
    __bf16* a_bf = (__bf16*)((char*)d_ws + (size_t)4 * 1024 * 1024);
    __bf16* z3   = a_bf;
    float*  z1   = (float*)((char*)d_ws + (size_t)6 * 1024 * 1024);
    float*  z2   = z1 + 32 * 56 * 512;
    __bf16* w_bf = (__bf16*)((char*)d_ws + (size_t)10 * 1024 * 1024);

    const bool cacheW = ws_size >= (size_t)266 * 1024 * 1024;

    if (cacheW)
        wconv_kernel<<<65536, 256, 0, stream>>>(IN(31), w_bf);

    head_kernel<<<16384, 64, 0, stream>>>(
        IN(0), IN(1), IN(2), IN(3), IN(4), IN(5), IN(6), IN(7), IN(8), IN(9), IN(10),
        IN(11), IN(12), IN(13), IN(14), IN(15), IN(16), IN(17), IN(18), cpt);

    for (int it = 0; it < 4; ++it) {
        prep_kernel<<<4096, 256, 0, stream>>>(cpt, IN(19), IN(20), IN(21), IN(22),
                                              IN(32), a_bf, z2);
        if (cacheW)
            gemm_lds_kernel<<<512, 256, 0, stream>>>(a_bf, w_bf, z2);
        else
            gemm_kernel<<<512, 256, 0, stream>>>(a_bf, IN(31), z2);
        conv1_kernel<<<dim3(32, 14), 512, 0, stream>>>(cpt, IN(19), IN(20), IN(21), IN(22),
                                                       IN(23), IN(24), z1);
        prep2_kernel<<<4096, 256, 0, stream>>>(z1, z2, IN(25), IN(26), IN(27), IN(28), z3);
        conv2_kernel<<<dim3(32, 16), 512, 0, stream>>>(z3, IN(29), IN(30), cpt);
    }

    tail_kernel<<<64, 256, 0, stream>>>(cpt, IN(33), IN(34), IN(35), IN(36),
                                        IN(37), IN(38), (float*)d_out);
#undef IN
}

// Round 3
// 1727.914 us; speedup vs baseline: 1.0878x; 1.0605x over previous
//
#include <hip/hip_runtime.h>
#include <cmath>
#include <cstdint>

typedef __bf16 bf16x8 __attribute__((ext_vector_type(8)));
typedef float  f32x4  __attribute__((ext_vector_type(4)));
typedef float  f32x16 __attribute__((ext_vector_type(16)));

#define EPSF 1e-5f
// B=32, total in-ch=65, H=32, W=16 -> 512 pixels. cpt: (32,64,32,16) fp32.
// GEMM: z2[32,4096] = a[32,32768] @ plus_w[4096,32768]^T, 4 iterations.
// plus_w fp32 (512 MiB) is re-tiled ONCE per call into MFMA-fragment order
// (bf16, 256 MiB workspace): wt[(nt*2048 + k16)*64 + lane][8] — so each GEMM
// wave streams a CONTIGUOUS 128 KiB region (1 KiB per K-step, lanes adjacent).
// The old row-major stream had 64 lanes at 64-KiB stride per instruction =
// same-HBM-channel scatter -> ~1 TB/s effective. Tiled stream is DRAM-linear.
// A (2 MiB) gets the same fragment tiling in prep (L2-broadcast across waves).

// async 16B global->LDS (LDS dest = wave-uniform base + lane*16; global src per-lane)
__device__ __forceinline__ void gll16(const void* g, void* l)
{
    __builtin_amdgcn_global_load_lds(
        reinterpret_cast<const __attribute__((address_space(1))) void*>(
            reinterpret_cast<uintptr_t>(g)),
        reinterpret_cast<__attribute__((address_space(3))) void*>(
            reinterpret_cast<uintptr_t>(l)),
        16, 0, 0);
}

// ---------------- head: convc/convp/convt + time MLP + poi + bn1(relu) + conv1 ----------------
__global__ __launch_bounds__(64) void head_kernel(
    const float* __restrict__ x,
    const float* __restrict__ cw, const float* __restrict__ cb,
    const float* __restrict__ pw, const float* __restrict__ pb,
    const float* __restrict__ tw, const float* __restrict__ tb,
    const float* __restrict__ tmw, const float* __restrict__ tmb,
    const float* __restrict__ tfw, const float* __restrict__ tfb,
    const float* __restrict__ poiw, const float* __restrict__ poib,
    const float* __restrict__ g1, const float* __restrict__ bb1,
    const float* __restrict__ m1, const float* __restrict__ v1,
    const float* __restrict__ w1, const float* __restrict__ b1c,
    float* __restrict__ cpt)
{
    int pix = blockIdx.x;            // 0..16383
    int b = pix >> 9, p = pix & 511;
    int t = threadIdx.x;             // 0..63

    __shared__ float xs[65];
    __shared__ float tx1[28];
    __shared__ float y[201];
    __shared__ float tx2s;

    for (int c = t; c < 65; c += 64)
        xs[c] = x[(b * 65 + c) * 512 + p];
    __syncthreads();

    if (t < 28) {
        float acc = tmb[t];
        for (int j = 0; j < 31; ++j) acc += tmw[t * 31 + j] * xs[34 + j];
        tx1[t] = fmaxf(acc, 0.f);
    }
    __syncthreads();
    if (t == 0) {
        float acc = tfb[0];
        for (int j = 0; j < 28; ++j) acc += tfw[j] * tx1[j];
        tx2s = fmaxf(acc, 0.f);
    }
    __syncthreads();
    float tx2 = tx2s;

    { // closeness: out ch 0..63, K=6 (x ch 0..5)
        float acc = cb[t];
        for (int j = 0; j < 6; ++j) acc += cw[t * 6 + j] * xs[j];
        y[t] = acc;
    }
    { // period: out ch 64..127, K=8 (x ch 6..13)
        float acc = pb[t];
        for (int j = 0; j < 8; ++j) acc += pw[t * 8 + j] * xs[6 + j];
        y[64 + t] = acc;
    }
    { // trend: out ch 128..191, K=8 (x ch 14..21)
        float acc = tb[t];
        for (int j = 0; j < 8; ++j) acc += tw[t * 8 + j] * xs[14 + j];
        y[128 + t] = acc;
    }
    if (t < 9) { // poi_time: out ch 192..200 (poi = x ch 22..33)
        float acc = poib[t];
        for (int j = 0; j < 12; ++j) acc += poiw[t * 12 + j] * (tx2 * xs[22 + j]);
        y[192 + t] = acc;
    }
    // bn1(relu(.)) applied by the same thread that wrote each channel
    for (int c = t; c < 201; c += 64) {
        float s  = g1[c] * rsqrtf(v1[c] + EPSF);
        float tt = bb1[c] - m1[c] * s;
        y[c] = fmaxf(y[c], 0.f) * s + tt;
    }
    __syncthreads();

    float acc = b1c[t];
    const float* wrow = w1 + t * 201;
    for (int c = 0; c < 201; ++c) acc += wrow[c] * y[c];
    cpt[(b * 64 + t) * 512 + p] = acc;
}

// ---------------- wconv_tiled: plus_w fp32 -> bf16 MFMA-fragment tiling (once per call) --------
// Layout: wt element ((nt*2048 + g16)*64 + l)*8 + e = W[nt*32 + (l&31)][g16*16 + (l>>5)*8 + e].
// Block (nt, kg): rows nt*32..+32, k = kg*512..+512. Coalesced reads, LDS reorder, coalesced writes.
__global__ __launch_bounds__(256) void wconv_tiled_kernel(const float* __restrict__ w,
                                                          __bf16* __restrict__ wt)
{
    __shared__ __bf16 lds[32 * 528];   // 32 local-g16 groups x (512 data + 16 pad)
    int nt = blockIdx.x;               // 0..127
    int kg = blockIdx.y;               // 0..63
    int t  = threadIdx.x;              // 0..255

    // phase 1: read rows coalesced (8 B/lane), convert, scatter to LDS tiled order
    int klo  = t * 2;                  // local k, 0..510
    int g16l = klo >> 4;
    int hi   = (klo >> 3) & 1;
    int e    = klo & 7;                // even
    __bf16* d = &lds[g16l * 528 + hi * 256 + e];
    const float* src0 = w + (long)(nt * 32) * 32768 + kg * 512 + klo;
    for (int r = 0; r < 32; ++r) {
        float2 v = *(const float2*)(src0 + (long)r * 32768);
        d[r * 8 + 0] = (__bf16)v.x;
        d[r * 8 + 1] = (__bf16)v.y;
    }
    __syncthreads();

    // phase 2: write 2048 x 16B fragments, fully coalesced & contiguous
    long obase = (long)(nt * 2048 + kg * 32) * 512;   // bf16 elements
#pragma unroll
    for (int j = 0; j < 8; ++j) {
        int fid = j * 256 + t;         // 0..2047 = g16l*64 + l
        int gl = fid >> 6;
        int l  = fid & 63;
        bf16x8 v = *(const bf16x8*)&lds[gl * 528 + (l >> 5) * 256 + (l & 31) * 8];
        *(bf16x8*)(wt + obase + (long)fid * 8) = v;
    }
}

// ---------------- prep_tiled: a_t = bn1(relu(cpt)) as bf16 in fragment tiling; z2 = plus_b ----
// a_t element (g16*64 + hi*32 + b)*8 + e = A[b][k], k = g16*16 + hi*8 + e, k = c*512 + p.
__global__ void prep_tiled_kernel(const float* __restrict__ cpt,
                                  const float* __restrict__ g, const float* __restrict__ bb,
                                  const float* __restrict__ m, const float* __restrict__ v,
                                  const float* __restrict__ plus_b,
                                  __bf16* __restrict__ a_t, float* __restrict__ z2)
{
    int i = blockIdx.x * blockDim.x + threadIdx.x;
    if (i < 32 * 64 * 512) {
        int b = i >> 15, c = (i >> 9) & 63, p = i & 511;
        float s  = g[c] * rsqrtf(v[c] + EPSF);
        float tt = bb[c] - m[c] * s;
        float val = fmaxf(cpt[i], 0.f) * s + tt;
        int k = c * 512 + p;
        int idx = ((k >> 4) * 64 + ((k >> 3) & 1) * 32 + b) * 8 + (k & 7);
        a_t[idx] = (__bf16)val;
    }
    if (i < 32 * 4096) {
        z2[i] = plus_b[i & 4095];
    }
}

// ---------------- prep (fallback, linear A layout) ----------------
__global__ void prep_kernel(const float* __restrict__ cpt,
                            const float* __restrict__ g, const float* __restrict__ bb,
                            const float* __restrict__ m, const float* __restrict__ v,
                            const float* __restrict__ plus_b,
                            __bf16* __restrict__ a_bf, float* __restrict__ z2)
{
    int i = blockIdx.x * blockDim.x + threadIdx.x;
    if (i < 32 * 64 * 512) {
        int c = (i >> 9) & 63;
        float s  = g[c] * rsqrtf(v[c] + EPSF);
        float tt = bb[c] - m[c] * s;
        a_bf[i] = (__bf16)(fmaxf(cpt[i], 0.f) * s + tt);
    }
    if (i < 32 * 4096) {
        z2[i] = plus_b[i & 4095];
    }
}

// ---------------- GEMM (fallback, fp32 W stream): used only if ws can't hold wt ----------------
__global__ __launch_bounds__(256) void gemm_kernel(const __bf16* __restrict__ a_bf,
                                                   const float* __restrict__ plus_w,
                                                   float* __restrict__ z2)
{
    int wave = threadIdx.x >> 6;
    int lane = threadIdx.x & 63;
    int gw = blockIdx.x * 4 + wave;   // 0..2047
    int nt = gw & 127;                // 128 n-tiles of 32
    int ks = gw >> 7;                 // 16 K-splits of 2048
    int r32 = lane & 31;
    int hi  = lane >> 5;
    int n = nt * 32 + r32;
    long k0 = (long)ks * 2048 + hi * 8;

    const float*  wp = plus_w + (long)n * 32768 + k0;
    const bf16x8* ap = (const bf16x8*)(a_bf + (long)r32 * 32768 + k0);

    f32x16 acc = {};
#pragma unroll 4
    for (int it = 0; it < 128; ++it) {          // 128 * K16 = 2048
        f32x4 w0 = *(const f32x4*)(wp + it * 16);
        f32x4 w1 = *(const f32x4*)(wp + it * 16 + 4);
        bf16x8 bfr;
#pragma unroll
        for (int j = 0; j < 4; ++j) { bfr[j] = (__bf16)w0[j]; bfr[j + 4] = (__bf16)w1[j]; }
        bf16x8 afr = ap[it * 2];
        acc = __builtin_amdgcn_mfma_f32_32x32x16_bf16(afr, bfr, acc, 0, 0, 0);
    }
#pragma unroll
    for (int r = 0; r < 16; ++r) {
        int brow = (r & 3) + 8 * (r >> 2) + 4 * hi;
        atomicAdd(&z2[brow * 4096 + n], acc[r]);
    }
}

// ---------------- GEMM (tiled bf16 W + tiled A, LDS-ring deep pipeline) ----------------
// 512 blocks x 4 waves; wave = one 32-col n-tile x one K-split of 2048.
// W stream per wave is CONTIGUOUS 128 KiB (1 KiB per K-step, lane-adjacent).
// A fragments contiguous too; shared across the 128 same-ks waves via L2.
// Ring: 8 slots x 1 KiB each for W and A, filled by global_load_lds, counted vmcnt.
__global__ __launch_bounds__(256) void gemm_lds_kernel(const __bf16* __restrict__ a_t,
                                                       const __bf16* __restrict__ w_t,
                                                       float* __restrict__ z2)
{
    __shared__ __bf16 ring[4][2][8][512];   // [wave][W/A][slot][lane*8] = 64 KiB

    int wave = threadIdx.x >> 6;
    int lane = threadIdx.x & 63;
    int gw = blockIdx.x * 4 + wave;   // 0..2047
    int nt = gw & 127;                // n-tile of 32 cols
    int ks = gw >> 7;                 // K-split of 2048
    int r32 = lane & 31;
    int hi  = lane >> 5;
    int n = nt * 32 + r32;

    // per-lane fragment sources: +it*512 elements per K-step, lane-contiguous
    const __bf16* wsrc = w_t + (long)(nt * 2048 + ks * 128) * 512 + lane * 8;
    const __bf16* asrc = a_t + (long)(ks * 128) * 512 + lane * 8;
    __bf16* wr = &ring[wave][0][0][0];
    __bf16* ar = &ring[wave][1][0][0];

    // prologue: fill all 8 slots (16 outstanding glls, pair order W,A per slot)
#pragma unroll
    for (int s = 0; s < 8; ++s) {
        gll16(wsrc + s * 512, wr + s * 512);
        gll16(asrc + s * 512, ar + s * 512);
    }

    f32x16 acc = {};
    // steady state: wait oldest pair, consume, reissue slot for it+8
    for (int it = 0; it < 120; ++it) {
        int slot = it & 7;
        asm volatile("s_waitcnt vmcnt(14)" ::: "memory");
        __builtin_amdgcn_sched_barrier(0);
        bf16x8 bfr = *(const bf16x8*)(wr + slot * 512 + lane * 8);
        bf16x8 afr = *(const bf16x8*)(ar + slot * 512 + lane * 8);
        acc = __builtin_amdgcn_mfma_f32_32x32x16_bf16(afr, bfr, acc, 0, 0, 0);
        gll16(wsrc + (it + 8) * 512, wr + slot * 512);
        gll16(asrc + (it + 8) * 512, ar + slot * 512);
    }
    // tail: drain and consume last 8 slots
    asm volatile("s_waitcnt vmcnt(0)" ::: "memory");
    __builtin_amdgcn_sched_barrier(0);
#pragma unroll
    for (int it = 120; it < 128; ++it) {
        int slot = it & 7;
        bf16x8 bfr = *(const bf16x8*)(wr + slot * 512 + lane * 8);
        bf16x8 afr = *(const bf16x8*)(ar + slot * 512 + lane * 8);
        acc = __builtin_amdgcn_mfma_f32_32x32x16_bf16(afr, bfr, acc, 0, 0, 0);
    }

    // C/D layout (m74/m101): col(n)=lane&31, row(b)=(reg&3)+8*(reg>>2)+4*(lane>>5)
#pragma unroll
    for (int r = 0; r < 16; ++r) {
        int brow = (r & 3) + 8 * (r >> 2) + 4 * hi;
        atomicAdd(&z2[brow * 4096 + n], acc[r]);
    }
}

// ---------------- conv3x3 #1: z1 = conv(relu(bn1(cpt)), rp_conv1_w) + b, 56 out ch ----------------
__global__ __launch_bounds__(512) void conv1_kernel(const float* __restrict__ cpt,
                                                    const float* __restrict__ g, const float* __restrict__ bb,
                                                    const float* __restrict__ m, const float* __restrict__ v,
                                                    const float* __restrict__ w,
                                                    const float* __restrict__ bias,
                                                    float* __restrict__ z1)
{
    int b  = blockIdx.x;        // 0..31
    int og = blockIdx.y;        // 0..13 (4 out-ch each)
    int p  = threadIdx.x;       // 0..511
    int h = p >> 4, wc = p & 15;
    int o0 = og * 4;

    __shared__ float ss[64], ts[64];
    if (p < 64) {
        float s = g[p] * rsqrtf(v[p] + EPSF);
        ss[p] = s;
        ts[p] = bb[p] - m[p] * s;
    }
    __syncthreads();

    float a0 = bias[o0], a1 = bias[o0 + 1], a2 = bias[o0 + 2], a3 = bias[o0 + 3];
    const float* rb = cpt + b * 64 * 512;
    for (int c = 0; c < 64; ++c) {
        const float* rc = rb + c * 512;
        float s = ss[c], tt = ts[c];
        float rv[9];
#pragma unroll
        for (int dh = -1; dh <= 1; ++dh)
#pragma unroll
            for (int dw = -1; dw <= 1; ++dw) {
                int hh = h + dh, ww = wc + dw;
                bool ok = (hh >= 0) & (hh < 32) & (ww >= 0) & (ww < 16);
                rv[(dh + 1) * 3 + (dw + 1)] = ok ? fmaxf(rc[hh * 16 + ww] * s + tt, 0.f) : 0.f;
            }
#pragma unroll
        for (int tp = 0; tp < 9; ++tp) {
            a0 += rv[tp] * w[((o0    ) * 64 + c) * 9 + tp];
            a1 += rv[tp] * w[((o0 + 1) * 64 + c) * 9 + tp];
            a2 += rv[tp] * w[((o0 + 2) * 64 + c) * 9 + tp];
            a3 += rv[tp] * w[((o0 + 3) * 64 + c) * 9 + tp];
        }
    }
    float* zb = z1 + ((b * 56 + o0) * 512) + p;
    zb[0] = a0; zb[512] = a1; zb[1024] = a2; zb[1536] = a3;
}

// ---------------- prep2: z3 = relu(bn2(concat(z1, z2))) -> bf16 ----------------
__global__ void prep2_kernel(const float* __restrict__ z1, const float* __restrict__ z2,
                             const float* __restrict__ g, const float* __restrict__ bb,
                             const float* __restrict__ m, const float* __restrict__ v,
                             __bf16* __restrict__ z3)
{
    int i = blockIdx.x * blockDim.x + threadIdx.x;
    if (i >= 32 * 64 * 512) return;
    int b = i >> 15, c = (i >> 9) & 63, p = i & 511;
    float val = (c < 56) ? z1[(b * 56 + c) * 512 + p]
                         : z2[b * 4096 + (c - 56) * 512 + p];
    float s  = g[c] * rsqrtf(v[c] + EPSF);
    float tt = bb[c] - m[c] * s;
    z3[i] = (__bf16)fmaxf(val * s + tt, 0.f);
}

// ---------------- conv3x3 #2: cpt += conv(z3, rp_conv2_w) + b (in-place residual) -----------
__global__ __launch_bounds__(512) void conv2_kernel(const __bf16* __restrict__ z3,
                                                    const float* __restrict__ w,
                                                    const float* __restrict__ bias,
                                                    float* __restrict__ cpt)
{
    int b  = blockIdx.x;        // 0..31
    int og = blockIdx.y;        // 0..15
    int p  = threadIdx.x;       // 0..511
    int h = p >> 4, wc = p & 15;
    int o0 = og * 4;
    float a0 = bias[o0], a1 = bias[o0 + 1], a2 = bias[o0 + 2], a3 = bias[o0 + 3];
    const __bf16* rb = z3 + b * 64 * 512;
    for (int c = 0; c < 64; ++c) {
        const __bf16* rc = rb + c * 512;
        float rv[9];
#pragma unroll
        for (int dh = -1; dh <= 1; ++dh)
#pragma unroll
            for (int dw = -1; dw <= 1; ++dw) {
                int hh = h + dh, ww = wc + dw;
                bool ok = (hh >= 0) & (hh < 32) & (ww >= 0) & (ww < 16);
                rv[(dh + 1) * 3 + (dw + 1)] = ok ? (float)rc[hh * 16 + ww] : 0.f;
            }
#pragma unroll
        for (int tp = 0; tp < 9; ++tp) {
            a0 += rv[tp] * w[((o0    ) * 64 + c) * 9 + tp];
            a1 += rv[tp] * w[((o0 + 1) * 64 + c) * 9 + tp];
            a2 += rv[tp] * w[((o0 + 2) * 64 + c) * 9 + tp];
            a3 += rv[tp] * w[((o0 + 3) * 64 + c) * 9 + tp];
        }
    }
    float* cb_ = cpt + ((b * 64 + o0) * 512) + p;
    cb_[0]    += a0;
    cb_[512]  += a1;
    cb_[1024] += a2;
    cb_[1536] += a3;
}

// ---------------- tail: out = tanh(conv2(bn2(relu(cpt)))) -> fp32 ----------------
__global__ void tail_kernel(const float* __restrict__ cpt,
                            const float* __restrict__ g, const float* __restrict__ bb,
                            const float* __restrict__ m, const float* __restrict__ v,
                            const float* __restrict__ w2, const float* __restrict__ b2,
                            float* __restrict__ out)
{
    int i = blockIdx.x * blockDim.x + threadIdx.x;
    if (i >= 32 * 512) return;
    int b = i >> 9, p = i & 511;
    float a0 = b2[0], a1 = b2[1];
    for (int c = 0; c < 64; ++c) {
        float s  = g[c] * rsqrtf(v[c] + EPSF);
        float tt = bb[c] - m[c] * s;
        float y = fmaxf(cpt[(b * 64 + c) * 512 + p], 0.f) * s + tt;
        a0 += w2[c] * y;
        a1 += w2[64 + c] * y;
    }
    out[(b * 2 + 0) * 512 + p] = tanhf(a0);
    out[(b * 2 + 1) * 512 + p] = tanhf(a1);
}

extern "C" void kernel_launch(void* const* d_in, const int* in_sizes, int n_in,
                              void* d_out, int out_size, void* d_ws, size_t ws_size,
                              hipStream_t stream)
{
#define IN(i) ((const float*)d_in[i])
    // workspace layout:
    //   [0,      4 MiB) cpt   : 32*64*512 fp32
    //   [4 MiB,  6 MiB) a_t   : 32*64*512 bf16 fragment-tiled GEMM A — ALIASED with z3
    //                           (safe: a_t consumed by gemm before prep2 writes z3;
    //                            z3 consumed by conv2 before next prep rewrites a_t)
    //   [6 MiB,  9.5MiB) z1   : 32*56*512 fp32
    //   [9.5MiB, 10 MiB) z2   : 32*4096  fp32
    //   [10 MiB, 266 MiB) w_t : 4096*32768 bf16 fragment-tiled plus_w, rebuilt every
    //                           call by wconv_tiled (re-poisoning harmless).
    float*  cpt  = (float*)d_ws;
    __bf16* a_t  = (__bf16*)((char*)d_ws + (size_t)4 * 1024 * 1024);
    __bf16* z3   = a_t;
    float*  z1   = (float*)((char*)d_ws + (size_t)6 * 1024 * 1024);
    float*  z2   = z1 + 32 * 56 * 512;
    __bf16* w_t  = (__bf16*)((char*)d_ws + (size_t)10 * 1024 * 1024);

    const bool cacheW = ws_size >= (size_t)266 * 1024 * 1024;

    if (cacheW)
        wconv_tiled_kernel<<<dim3(128, 64), 256, 0, stream>>>(IN(31), w_t);

    head_kernel<<<16384, 64, 0, stream>>>(
        IN(0), IN(1), IN(2), IN(3), IN(4), IN(5), IN(6), IN(7), IN(8), IN(9), IN(10),
        IN(11), IN(12), IN(13), IN(14), IN(15), IN(16), IN(17), IN(18), cpt);

    for (int it = 0; it < 4; ++it) {
        if (cacheW) {
            prep_tiled_kernel<<<4096, 256, 0, stream>>>(cpt, IN(19), IN(20), IN(21), IN(22),
                                                        IN(32), a_t, z2);
            gemm_lds_kernel<<<512, 256, 0, stream>>>(a_t, w_t, z2);
        } else {
            prep_kernel<<<4096, 256, 0, stream>>>(cpt, IN(19), IN(20), IN(21), IN(22),
                                                  IN(32), a_t, z2);
            gemm_kernel<<<512, 256, 0, stream>>>(a_t, IN(31), z2);
        }
        conv1_kernel<<<dim3(32, 14), 512, 0, stream>>>(cpt, IN(19), IN(20), IN(21), IN(22),
                                                       IN(23), IN(24), z1);
        prep2_kernel<<<4096, 256, 0, stream>>>(z1, z2, IN(25), IN(26), IN(27), IN(28), z3);
        conv2_kernel<<<dim3(32, 16), 512, 0, stream>>>(z3, IN(29), IN(30), cpt);
    }

    tail_kernel<<<64, 256, 0, stream>>>(cpt, IN(33), IN(34), IN(35), IN(36),
                                        IN(37), IN(38), (float*)d_out);
#undef IN
}

// Round 4
// 1723.294 us; speedup vs baseline: 1.0907x; 1.0027x over previous
//
#include <hip/hip_runtime.h>
#include <cmath>
#include <cstdint>

typedef __bf16 bf16x8 __attribute__((ext_vector_type(8)));
typedef float  f32x4  __attribute__((ext_vector_type(4)));
typedef float  f32x16 __attribute__((ext_vector_type(16)));

#define EPSF 1e-5f
// B=32, total in-ch=65, H=32, W=16 -> 512 pixels. cpt: (32,64,32,16) fp32.
// GEMM: z2[32,4096] = a[32,32768] @ plus_w[4096,32768]^T, 4 iterations.
// plus_w fp32 (512 MiB) is re-tiled ONCE per call into bf16 MFMA fragments with a
// K-STEP-INTERLEAVED order: fragment(nt,k16) lives at ((it*16+ks)*128 + nt)*1KiB,
// it=k16&127, ks=k16>>7. At GEMM step `it`, ALL 2048 waves read one contiguous
// 2 MiB window -> dense instantaneous HBM footprint (all channels), unlike the
// previous per-wave-contiguous layout whose 2^17-strided wave bases aliased onto
// few channels at a time (~0.85 TB/s). GEMM uses plain register loads (no LDS).

// ---------------- head: convc/convp/convt + time MLP + poi + bn1(relu) + conv1 ----------------
__global__ __launch_bounds__(64) void head_kernel(
    const float* __restrict__ x,
    const float* __restrict__ cw, const float* __restrict__ cb,
    const float* __restrict__ pw, const float* __restrict__ pb,
    const float* __restrict__ tw, const float* __restrict__ tb,
    const float* __restrict__ tmw, const float* __restrict__ tmb,
    const float* __restrict__ tfw, const float* __restrict__ tfb,
    const float* __restrict__ poiw, const float* __restrict__ poib,
    const float* __restrict__ g1, const float* __restrict__ bb1,
    const float* __restrict__ m1, const float* __restrict__ v1,
    const float* __restrict__ w1, const float* __restrict__ b1c,
    float* __restrict__ cpt)
{
    int pix = blockIdx.x;            // 0..16383
    int b = pix >> 9, p = pix & 511;
    int t = threadIdx.x;             // 0..63

    __shared__ float xs[65];
    __shared__ float tx1[28];
    __shared__ float y[201];
    __shared__ float tx2s;

    for (int c = t; c < 65; c += 64)
        xs[c] = x[(b * 65 + c) * 512 + p];
    __syncthreads();

    if (t < 28) {
        float acc = tmb[t];
        for (int j = 0; j < 31; ++j) acc += tmw[t * 31 + j] * xs[34 + j];
        tx1[t] = fmaxf(acc, 0.f);
    }
    __syncthreads();
    if (t == 0) {
        float acc = tfb[0];
        for (int j = 0; j < 28; ++j) acc += tfw[j] * tx1[j];
        tx2s = fmaxf(acc, 0.f);
    }
    __syncthreads();
    float tx2 = tx2s;

    { // closeness: out ch 0..63, K=6 (x ch 0..5)
        float acc = cb[t];
        for (int j = 0; j < 6; ++j) acc += cw[t * 6 + j] * xs[j];
        y[t] = acc;
    }
    { // period: out ch 64..127, K=8 (x ch 6..13)
        float acc = pb[t];
        for (int j = 0; j < 8; ++j) acc += pw[t * 8 + j] * xs[6 + j];
        y[64 + t] = acc;
    }
    { // trend: out ch 128..191, K=8 (x ch 14..21)
        float acc = tb[t];
        for (int j = 0; j < 8; ++j) acc += tw[t * 8 + j] * xs[14 + j];
        y[128 + t] = acc;
    }
    if (t < 9) { // poi_time: out ch 192..200 (poi = x ch 22..33)
        float acc = poib[t];
        for (int j = 0; j < 12; ++j) acc += poiw[t * 12 + j] * (tx2 * xs[22 + j]);
        y[192 + t] = acc;
    }
    // bn1(relu(.)) applied by the same thread that wrote each channel
    for (int c = t; c < 201; c += 64) {
        float s  = g1[c] * rsqrtf(v1[c] + EPSF);
        float tt = bb1[c] - m1[c] * s;
        y[c] = fmaxf(y[c], 0.f) * s + tt;
    }
    __syncthreads();

    float acc = b1c[t];
    const float* wrow = w1 + t * 201;
    for (int c = 0; c < 201; ++c) acc += wrow[c] * y[c];
    cpt[(b * 64 + t) * 512 + p] = acc;
}

// ---------------- wconv_tiled: plus_w fp32 -> bf16 K-interleaved MFMA fragments ----------------
// Fragment(nt, k16), element (l, e) = W[nt*32 + (l&31)][k16*16 + (l>>5)*8 + e],
// stored at wt[ ((it*16 + ks)*128 + nt)*512 + l*8 + e ], it = k16&127, ks = k16>>7.
// Block (nt, kg): rows nt*32..+32, k = kg*512..+512. Coalesced reads, LDS reorder,
// 1-KiB-contiguous fragment writes.
__global__ __launch_bounds__(256) void wconv_tiled_kernel(const float* __restrict__ w,
                                                          __bf16* __restrict__ wt)
{
    __shared__ __bf16 lds[32 * 528];   // 32 local-g16 groups x (512 data + 16 pad)
    int nt = blockIdx.x;               // 0..127
    int kg = blockIdx.y;               // 0..63
    int t  = threadIdx.x;              // 0..255

    // phase 1: read rows coalesced (8 B/lane), convert, scatter to LDS tiled order
    int klo  = t * 2;                  // local k, 0..510
    int g16l = klo >> 4;
    int hi   = (klo >> 3) & 1;
    int e    = klo & 7;                // even
    __bf16* d = &lds[g16l * 528 + hi * 256 + e];
    const float* src0 = w + (long)(nt * 32) * 32768 + kg * 512 + klo;
    for (int r = 0; r < 32; ++r) {
        float2 v = *(const float2*)(src0 + (long)r * 32768);
        d[r * 8 + 0] = (__bf16)v.x;
        d[r * 8 + 1] = (__bf16)v.y;
    }
    __syncthreads();

    // phase 2: write 2048 x 16B fragment pieces; each wave writes one contiguous 1 KiB
#pragma unroll
    for (int j = 0; j < 8; ++j) {
        int fid = j * 256 + t;         // 0..2047 = gl*64 + l
        int gl = fid >> 6;             // local k16 index 0..31
        int l  = fid & 63;
        int k16 = kg * 32 + gl;        // global k16, 0..2047
        int it  = k16 & 127;
        int ks  = k16 >> 7;
        bf16x8 v = *(const bf16x8*)&lds[gl * 528 + (l >> 5) * 256 + (l & 31) * 8];
        long off = ((long)(it * 16 + ks) * 128 + nt) * 512 + l * 8;
        *(bf16x8*)(wt + off) = v;
    }
}

// ---------------- prep_tiled: a_t = bn1(relu(cpt)) as bf16, k-major fragment layout ----------
// a_t element (k16*64 + hi*32 + b)*8 + e = A[b][k], k = k16*16 + hi*8 + e, k = c*512 + p.
__global__ void prep_tiled_kernel(const float* __restrict__ cpt,
                                  const float* __restrict__ g, const float* __restrict__ bb,
                                  const float* __restrict__ m, const float* __restrict__ v,
                                  const float* __restrict__ plus_b,
                                  __bf16* __restrict__ a_t, float* __restrict__ z2)
{
    int i = blockIdx.x * blockDim.x + threadIdx.x;
    if (i < 32 * 64 * 512) {
        int b = i >> 15, c = (i >> 9) & 63, p = i & 511;
        float s  = g[c] * rsqrtf(v[c] + EPSF);
        float tt = bb[c] - m[c] * s;
        float val = fmaxf(cpt[i], 0.f) * s + tt;
        int k = c * 512 + p;
        int idx = ((k >> 4) * 64 + ((k >> 3) & 1) * 32 + b) * 8 + (k & 7);
        a_t[idx] = (__bf16)val;
    }
    if (i < 32 * 4096) {
        z2[i] = plus_b[i & 4095];
    }
}

// ---------------- prep (fallback, linear A layout) ----------------
__global__ void prep_kernel(const float* __restrict__ cpt,
                            const float* __restrict__ g, const float* __restrict__ bb,
                            const float* __restrict__ m, const float* __restrict__ v,
                            const float* __restrict__ plus_b,
                            __bf16* __restrict__ a_bf, float* __restrict__ z2)
{
    int i = blockIdx.x * blockDim.x + threadIdx.x;
    if (i < 32 * 64 * 512) {
        int c = (i >> 9) & 63;
        float s  = g[c] * rsqrtf(v[c] + EPSF);
        float tt = bb[c] - m[c] * s;
        a_bf[i] = (__bf16)(fmaxf(cpt[i], 0.f) * s + tt);
    }
    if (i < 32 * 4096) {
        z2[i] = plus_b[i & 4095];
    }
}

// ---------------- GEMM (fallback, fp32 W stream): used only if ws can't hold wt ----------------
__global__ __launch_bounds__(256) void gemm_kernel(const __bf16* __restrict__ a_bf,
                                                   const float* __restrict__ plus_w,
                                                   float* __restrict__ z2)
{
    int wave = threadIdx.x >> 6;
    int lane = threadIdx.x & 63;
    int gw = blockIdx.x * 4 + wave;   // 0..2047
    int nt = gw & 127;                // 128 n-tiles of 32
    int ks = gw >> 7;                 // 16 K-splits of 2048
    int r32 = lane & 31;
    int hi  = lane >> 5;
    int n = nt * 32 + r32;
    long k0 = (long)ks * 2048 + hi * 8;

    const float*  wp = plus_w + (long)n * 32768 + k0;
    const bf16x8* ap = (const bf16x8*)(a_bf + (long)r32 * 32768 + k0);

    f32x16 acc = {};
#pragma unroll 4
    for (int it = 0; it < 128; ++it) {          // 128 * K16 = 2048
        f32x4 w0 = *(const f32x4*)(wp + it * 16);
        f32x4 w1 = *(const f32x4*)(wp + it * 16 + 4);
        bf16x8 bfr;
#pragma unroll
        for (int j = 0; j < 4; ++j) { bfr[j] = (__bf16)w0[j]; bfr[j + 4] = (__bf16)w1[j]; }
        bf16x8 afr = ap[it * 2];
        acc = __builtin_amdgcn_mfma_f32_32x32x16_bf16(afr, bfr, acc, 0, 0, 0);
    }
#pragma unroll
    for (int r = 0; r < 16; ++r) {
        int brow = (r & 3) + 8 * (r >> 2) + 4 * hi;
        atomicAdd(&z2[brow * 4096 + n], acc[r]);
    }
}

// ---------------- GEMM (K-interleaved bf16 fragments, plain register loads) ----------------
// 512 blocks x 4 waves; wave = one 32-col n-tile x one K-split of 2048 (128 steps).
// Step it: W fragment at ((it*16+ks)*128 + nt)*512 + lane*8 — all 2048 waves read the
// same contiguous 2 MiB window per step. A fragment at (ks*128+it)*512 + lane*8 (L2-hot).
// No LDS; compiler software-pipelines the loads (unroll 8 ≈ 16 KiB in flight per wave).
__global__ __launch_bounds__(256) void gemm_reg_kernel(const __bf16* __restrict__ a_t,
                                                       const __bf16* __restrict__ w_t,
                                                       float* __restrict__ z2)
{
    int wave = threadIdx.x >> 6;
    int lane = threadIdx.x & 63;
    int gw = blockIdx.x * 4 + wave;   // 0..2047
    int nt = gw & 127;                // n-tile of 32 cols
    int ks = gw >> 7;                 // K-split of 2048
    int r32 = lane & 31;
    int hi  = lane >> 5;
    int n = nt * 32 + r32;

    // bf16x8-unit pointers; strides in units of 16 B
    const bf16x8* ap = (const bf16x8*)(a_t + (long)(ks * 128) * 512 + lane * 8);
    const bf16x8* wp = (const bf16x8*)(w_t + ((long)ks * 128 + nt) * 512 + lane * 8);

    f32x16 acc = {};
#pragma unroll 8
    for (int it = 0; it < 128; ++it) {
        bf16x8 afr = ap[(long)it * 64];        // +512 bf16 per step (contiguous per wave)
        bf16x8 bfr = wp[(long)it * 131072];    // +2 MiB per step (dense across waves)
        acc = __builtin_amdgcn_mfma_f32_32x32x16_bf16(afr, bfr, acc, 0, 0, 0);
    }

    // C/D layout (m74/m101): col(n)=lane&31, row(b)=(reg&3)+8*(reg>>2)+4*(lane>>5)
#pragma unroll
    for (int r = 0; r < 16; ++r) {
        int brow = (r & 3) + 8 * (r >> 2) + 4 * hi;
        atomicAdd(&z2[brow * 4096 + n], acc[r]);
    }
}

// ---------------- conv3x3 #1: z1 = conv(relu(bn1(cpt)), rp_conv1_w) + b, 56 out ch ----------------
__global__ __launch_bounds__(512) void conv1_kernel(const float* __restrict__ cpt,
                                                    const float* __restrict__ g, const float* __restrict__ bb,
                                                    const float* __restrict__ m, const float* __restrict__ v,
                                                    const float* __restrict__ w,
                                                    const float* __restrict__ bias,
                                                    float* __restrict__ z1)
{
    int b  = blockIdx.x;        // 0..31
    int og = blockIdx.y;        // 0..13 (4 out-ch each)
    int p  = threadIdx.x;       // 0..511
    int h = p >> 4, wc = p & 15;
    int o0 = og * 4;

    __shared__ float ss[64], ts[64];
    if (p < 64) {
        float s = g[p] * rsqrtf(v[p] + EPSF);
        ss[p] = s;
        ts[p] = bb[p] - m[p] * s;
    }
    __syncthreads();

    float a0 = bias[o0], a1 = bias[o0 + 1], a2 = bias[o0 + 2], a3 = bias[o0 + 3];
    const float* rb = cpt + b * 64 * 512;
    for (int c = 0; c < 64; ++c) {
        const float* rc = rb + c * 512;
        float s = ss[c], tt = ts[c];
        float rv[9];
#pragma unroll
        for (int dh = -1; dh <= 1; ++dh)
#pragma unroll
            for (int dw = -1; dw <= 1; ++dw) {
                int hh = h + dh, ww = wc + dw;
                bool ok = (hh >= 0) & (hh < 32) & (ww >= 0) & (ww < 16);
                rv[(dh + 1) * 3 + (dw + 1)] = ok ? fmaxf(rc[hh * 16 + ww] * s + tt, 0.f) : 0.f;
            }
#pragma unroll
        for (int tp = 0; tp < 9; ++tp) {
            a0 += rv[tp] * w[((o0    ) * 64 + c) * 9 + tp];
            a1 += rv[tp] * w[((o0 + 1) * 64 + c) * 9 + tp];
            a2 += rv[tp] * w[((o0 + 2) * 64 + c) * 9 + tp];
            a3 += rv[tp] * w[((o0 + 3) * 64 + c) * 9 + tp];
        }
    }
    float* zb = z1 + ((b * 56 + o0) * 512) + p;
    zb[0] = a0; zb[512] = a1; zb[1024] = a2; zb[1536] = a3;
}

// ---------------- prep2: z3 = relu(bn2(concat(z1, z2))) -> bf16 ----------------
__global__ void prep2_kernel(const float* __restrict__ z1, const float* __restrict__ z2,
                             const float* __restrict__ g, const float* __restrict__ bb,
                             const float* __restrict__ m, const float* __restrict__ v,
                             __bf16* __restrict__ z3)
{
    int i = blockIdx.x * blockDim.x + threadIdx.x;
    if (i >= 32 * 64 * 512) return;
    int b = i >> 15, c = (i >> 9) & 63, p = i & 511;
    float val = (c < 56) ? z1[(b * 56 + c) * 512 + p]
                         : z2[b * 4096 + (c - 56) * 512 + p];
    float s  = g[c] * rsqrtf(v[c] + EPSF);
    float tt = bb[c] - m[c] * s;
    z3[i] = (__bf16)fmaxf(val * s + tt, 0.f);
}

// ---------------- conv3x3 #2: cpt += conv(z3, rp_conv2_w) + b (in-place residual) -----------
__global__ __launch_bounds__(512) void conv2_kernel(const __bf16* __restrict__ z3,
                                                    const float* __restrict__ w,
                                                    const float* __restrict__ bias,
                                                    float* __restrict__ cpt)
{
    int b  = blockIdx.x;        // 0..31
    int og = blockIdx.y;        // 0..15
    int p  = threadIdx.x;       // 0..511
    int h = p >> 4, wc = p & 15;
    int o0 = og * 4;
    float a0 = bias[o0], a1 = bias[o0 + 1], a2 = bias[o0 + 2], a3 = bias[o0 + 3];
    const __bf16* rb = z3 + b * 64 * 512;
    for (int c = 0; c < 64; ++c) {
        const __bf16* rc = rb + c * 512;
        float rv[9];
#pragma unroll
        for (int dh = -1; dh <= 1; ++dh)
#pragma unroll
            for (int dw = -1; dw <= 1; ++dw) {
                int hh = h + dh, ww = wc + dw;
                bool ok = (hh >= 0) & (hh < 32) & (ww >= 0) & (ww < 16);
                rv[(dh + 1) * 3 + (dw + 1)] = ok ? (float)rc[hh * 16 + ww] : 0.f;
            }
#pragma unroll
        for (int tp = 0; tp < 9; ++tp) {
            a0 += rv[tp] * w[((o0    ) * 64 + c) * 9 + tp];
            a1 += rv[tp] * w[((o0 + 1) * 64 + c) * 9 + tp];
            a2 += rv[tp] * w[((o0 + 2) * 64 + c) * 9 + tp];
            a3 += rv[tp] * w[((o0 + 3) * 64 + c) * 9 + tp];
        }
    }
    float* cb_ = cpt + ((b * 64 + o0) * 512) + p;
    cb_[0]    += a0;
    cb_[512]  += a1;
    cb_[1024] += a2;
    cb_[1536] += a3;
}

// ---------------- tail: out = tanh(conv2(bn2(relu(cpt)))) -> fp32 ----------------
__global__ void tail_kernel(const float* __restrict__ cpt,
                            const float* __restrict__ g, const float* __restrict__ bb,
                            const float* __restrict__ m, const float* __restrict__ v,
                            const float* __restrict__ w2, const float* __restrict__ b2,
                            float* __restrict__ out)
{
    int i = blockIdx.x * blockDim.x + threadIdx.x;
    if (i >= 32 * 512) return;
    int b = i >> 9, p = i & 511;
    float a0 = b2[0], a1 = b2[1];
    for (int c = 0; c < 64; ++c) {
        float s  = g[c] * rsqrtf(v[c] + EPSF);
        float tt = bb[c] - m[c] * s;
        float y = fmaxf(cpt[(b * 64 + c) * 512 + p], 0.f) * s + tt;
        a0 += w2[c] * y;
        a1 += w2[64 + c] * y;
    }
    out[(b * 2 + 0) * 512 + p] = tanhf(a0);
    out[(b * 2 + 1) * 512 + p] = tanhf(a1);
}

extern "C" void kernel_launch(void* const* d_in, const int* in_sizes, int n_in,
                              void* d_out, int out_size, void* d_ws, size_t ws_size,
                              hipStream_t stream)
{
#define IN(i) ((const float*)d_in[i])
    // workspace layout:
    //   [0,      4 MiB) cpt   : 32*64*512 fp32
    //   [4 MiB,  6 MiB) a_t   : 32*64*512 bf16 fragment-tiled GEMM A — ALIASED with z3
    //                           (safe: a_t consumed by gemm before prep2 writes z3;
    //                            z3 consumed by conv2 before next prep rewrites a_t)
    //   [6 MiB,  9.5MiB) z1   : 32*56*512 fp32
    //   [9.5MiB, 10 MiB) z2   : 32*4096  fp32
    //   [10 MiB, 266 MiB) w_t : 4096*32768 bf16 K-interleaved fragment-tiled plus_w,
    //                           rebuilt every call by wconv_tiled (re-poisoning harmless).
    float*  cpt  = (float*)d_ws;
    __bf16* a_t  = (__bf16*)((char*)d_ws + (size_t)4 * 1024 * 1024);
    __bf16* z3   = a_t;
    float*  z1   = (float*)((char*)d_ws + (size_t)6 * 1024 * 1024);
    float*  z2   = z1 + 32 * 56 * 512;
    __bf16* w_t  = (__bf16*)((char*)d_ws + (size_t)10 * 1024 * 1024);

    const bool cacheW = ws_size >= (size_t)266 * 1024 * 1024;

    if (cacheW)
        wconv_tiled_kernel<<<dim3(128, 64), 256, 0, stream>>>(IN(31), w_t);

    head_kernel<<<16384, 64, 0, stream>>>(
        IN(0), IN(1), IN(2), IN(3), IN(4), IN(5), IN(6), IN(7), IN(8), IN(9), IN(10),
        IN(11), IN(12), IN(13), IN(14), IN(15), IN(16), IN(17), IN(18), cpt);

    for (int it = 0; it < 4; ++it) {
        if (cacheW) {
            prep_tiled_kernel<<<4096, 256, 0, stream>>>(cpt, IN(19), IN(20), IN(21), IN(22),
                                                        IN(32), a_t, z2);
            gemm_reg_kernel<<<512, 256, 0, stream>>>(a_t, w_t, z2);
        } else {
            prep_kernel<<<4096, 256, 0, stream>>>(cpt, IN(19), IN(20), IN(21), IN(22),
                                                  IN(32), a_t, z2);
            gemm_kernel<<<512, 256, 0, stream>>>(a_t, IN(31), z2);
        }
        conv1_kernel<<<dim3(32, 14), 512, 0, stream>>>(cpt, IN(19), IN(20), IN(21), IN(22),
                                                       IN(23), IN(24), z1);
        prep2_kernel<<<4096, 256, 0, stream>>>(z1, z2, IN(25), IN(26), IN(27), IN(28), z3);
        conv2_kernel<<<dim3(32, 16), 512, 0, stream>>>(z3, IN(29), IN(30), cpt);
    }

    tail_kernel<<<64, 256, 0, stream>>>(cpt, IN(33), IN(34), IN(35), IN(36),
                                        IN(37), IN(38), (float*)d_out);
#undef IN
}